// Round 9
// baseline (703.332 us; speedup 1.0000x reference)
//
#include <hip/hip_runtime.h>
#include <hip/hip_bf16.h>
#include <stdint.h>

#define DIM 2048
#define HID 5632
#define PDIM 2176   // padded row stride (elems for bf16 A, bytes for u8 B)

typedef __attribute__((ext_vector_type(8))) short short8;
typedef __attribute__((ext_vector_type(4))) float f32x4;
typedef __attribute__((ext_vector_type(4))) int int4v;
typedef __attribute__((ext_vector_type(4))) unsigned short ushort4v;
typedef __attribute__((ext_vector_type(4))) unsigned char uchar4v;
typedef __attribute__((ext_vector_type(2))) unsigned int u32x2;

__device__ __forceinline__ unsigned short f32_to_bf16_rne(float f) {
    union { float f; unsigned u; } v; v.f = f;
    unsigned u = v.u;
    return (unsigned short)((u + 0x7FFFu + ((u >> 16) & 1u)) >> 16);
}

__device__ __forceinline__ void gload16(const void* g, void* l) {
    __builtin_amdgcn_global_load_lds(
        (const __attribute__((address_space(1))) void*)g,
        (__attribute__((address_space(3))) void*)l,
        16, 0, 0);
}

// 8 packed uint8 -> short8 bf16 holding (c - 128) EXACTLY (|c-128| <= 128, bf16-exact).
// Scale is applied in the epilogue (factors out of the k-sum).
__device__ __forceinline__ short8 deq8(u32x2 raw) {
    float f[8];
    #pragma unroll
    for (int j = 0; j < 2; ++j) {
        unsigned w = raw[j];
        f[4*j+0] = (float)(w & 0xffu);          // v_cvt_f32_ubyte0
        f[4*j+1] = (float)((w >> 8) & 0xffu);   // v_cvt_f32_ubyte1
        f[4*j+2] = (float)((w >> 16) & 0xffu);  // v_cvt_f32_ubyte2
        f[4*j+3] = (float)(w >> 24);            // v_cvt_f32_ubyte3
    }
    union { unsigned u[4]; short8 v; } cv;
    #pragma unroll
    for (int j = 0; j < 4; ++j) {
        float lo = f[2*j]   - 128.0f;
        float hi = f[2*j+1] - 128.0f;
        asm("v_cvt_pk_bf16_f32 %0, %1, %2" : "=v"(cv.u[j]) : "v"(lo), "v"(hi));
    }
    return cv.v;
}

#define PH_OPEN \
    __builtin_amdgcn_sched_barrier(0); \
    __builtin_amdgcn_s_barrier(); \
    asm volatile("s_waitcnt lgkmcnt(0)" ::: "memory"); \
    __builtin_amdgcn_sched_barrier(0); \
    __builtin_amdgcn_s_setprio(1);
#define PH_CLOSE \
    __builtin_amdgcn_s_setprio(0); \
    __builtin_amdgcn_sched_barrier(0); \
    __builtin_amdgcn_s_barrier(); \
    __builtin_amdgcn_sched_barrier(0);
#define PH_CLOSE_VM(N) \
    __builtin_amdgcn_s_setprio(0); \
    __builtin_amdgcn_sched_barrier(0); \
    asm volatile("s_waitcnt vmcnt(" #N ")" ::: "memory"); \
    __builtin_amdgcn_sched_barrier(0); \
    __builtin_amdgcn_s_barrier(); \
    __builtin_amdgcn_sched_barrier(0);

// ---- repack down weights: int32 -> uint8, plain [DIM][HID] ----
__global__ void repack_plain(const int* __restrict__ wq, unsigned char* __restrict__ out, long total) {
    long n4 = total >> 2;
    long stride = (long)gridDim.x * blockDim.x;
    for (long i = (long)blockIdx.x * blockDim.x + threadIdx.x; i < n4; i += stride) {
        int4v c = ((const int4v*)wq)[i];
        uchar4v o;
        o.x = (unsigned char)c.x; o.y = (unsigned char)c.y;
        o.z = (unsigned char)c.z; o.w = (unsigned char)c.w;
        ((uchar4v*)out)[i] = o;
    }
}

// ---- repack gate+up: int32 -> uint8 interleaved W' [2*HID][PDIM] + scales sWp[2*HID] ----
__global__ void repack_gateup(const int* __restrict__ wg, const float* __restrict__ sg,
                              const int* __restrict__ wu, const float* __restrict__ su,
                              unsigned char* __restrict__ out, float* __restrict__ sWp) {
    const long n4 = (long)HID * DIM / 4;
    long stride = (long)gridDim.x * blockDim.x;
    for (long i = (long)blockIdx.x * blockDim.x + threadIdx.x; i < n4; i += stride) {
        int r  = (int)(i >> 9);        // DIM/4 = 512 chunks per source row
        int c4 = (int)(i & 511);
        int rp = ((r >> 4) << 5) + (r & 15);
        int4v g = ((const int4v*)wg)[i];
        int4v u = ((const int4v*)wu)[i];
        uchar4v og, ou;
        og.x = (unsigned char)g.x; og.y = (unsigned char)g.y;
        og.z = (unsigned char)g.z; og.w = (unsigned char)g.w;
        ou.x = (unsigned char)u.x; ou.y = (unsigned char)u.y;
        ou.z = (unsigned char)u.z; ou.w = (unsigned char)u.w;
        *(uchar4v*)(out + (long)rp * PDIM + c4 * 4)        = og;
        *(uchar4v*)(out + (long)(rp + 16) * PDIM + c4 * 4) = ou;
        if (c4 == 0) { sWp[rp] = sg[r]; sWp[rp + 16] = su[r]; }
    }
}

// ---- x: f32 -> bf16, padded rows [M][PDIM] ----
__global__ void cast_f32_bf16(const float* __restrict__ in, unsigned short* __restrict__ out, long n) {
    long n4 = n >> 2;
    const int CPR = PDIM / 4;
    long stride = (long)gridDim.x * blockDim.x;
    for (long i = (long)blockIdx.x * blockDim.x + threadIdx.x; i < n4; i += stride) {
        f32x4 v = ((const f32x4*)in)[i];
        int r  = (int)(i >> 9);
        int c4 = (int)(i & 511);
        ushort4v o;
        o.x = f32_to_bf16_rne(v[0]);
        o.y = f32_to_bf16_rne(v[1]);
        o.z = f32_to_bf16_rne(v[2]);
        o.w = f32_to_bf16_rne(v[3]);
        ((ushort4v*)out)[(long)r * CPR + c4] = o;
    }
}

// =====================================================================
// 256x256 BK=64, 4-phase/K-tile, per-phase staging, counted vmcnt.
// A: bf16 LDS, 4 regions [256 rows][32 elems] = 16KB (2 gloads/stage).
// B: uint8 LDS, 4 regions [256 rows][32 B]   =  8KB (1 gload/stage),
//    in-register (c-128)->bf16 (exact); scale applied in epilogue.
// Steady-state invariant (per wave): entering tile t, 6 loads in flight
// = {A(t,1)x2, B(t,1), A(t+1,0)x2, B(t+1,0)}; k0(t) complete.
// Gates: vmcnt(6) at Q2/Q4 closes; tails 0 / 3. Prologue 9 -> vmcnt(6).
// 512 threads = 8 waves (2Mx4N), wave tile 128x64.
// A-frag row-step: 16 rows x 32 elems = 512 = <<9 (R7's <<10 was the NaN).
// =====================================================================

#define GEMM_PROLOGUE_COMMON(Aptr, Bptr, Sc, LDA, LDBB)                              \
    const int tid  = threadIdx.x;                                                    \
    const int lane = tid & 63;                                                       \
    const int wid  = tid >> 6;                                                       \
    const int wr   = wid >> 2;                                                       \
    const int wc   = wid & 3;                                                        \
    const int m0   = blockIdx.x << 8;                                                \
    const int n0   = blockIdx.y << 8;                                                \
    const int lr   = lane & 15;                                                      \
    const int kg   = lane >> 4;                                                      \
    const int ck   = ((kg ^ ((lr >> 1) & 3)) << 3);                                  \
    const int aboff = (wr * 128 + lr) * 32;                                          \
    const int bcol8 = ((((kg >> 1) ^ ((lr >> 2) & 1)) << 4) | ((kg & 1) << 3));      \
    const int bboff = (wc * 64 + lr) * 32 + bcol8;                                   \
    int srow[2], scol[2], sdst[2];                                                   \
    _Pragma("unroll")                                                                \
    for (int l = 0; l < 2; ++l) {                                                    \
        int p = tid + (l << 9);                                                      \
        srow[l] = p >> 2;                                                            \
        scol[l] = (((p & 3) ^ ((p >> 3) & 3)) << 3);                                 \
        sdst[l] = p << 3;                                                            \
    }                                                                                \
    const int brow = tid >> 1;                                                       \
    const int bsc  = (((tid & 1) ^ ((brow >> 2) & 1)) << 4);                         \
    auto STAGE_A = [&](int t, int kh) {                                              \
        if (t < NT) {                                                                \
            unsigned short* dst = As + ((((t & 1) << 1) | kh) << 13);                \
            _Pragma("unroll")                                                        \
            for (int l = 0; l < 2; ++l)                                              \
                gload16(Aptr + (size_t)(m0 + srow[l]) * LDA + (t << 6) + (kh << 5) + scol[l], \
                        dst + sdst[l]);                                              \
        }                                                                            \
    };                                                                               \
    auto STAGE_B = [&](int t, int kh) {                                              \
        if (t < NT) {                                                                \
            unsigned char* dst = Bs + ((((t & 1) << 1) | kh) << 13);                 \
            gload16(Bptr + (size_t)(n0 + brow) * LDBB + (t << 6) + (kh << 5) + bsc,  \
                    dst + (tid << 4));                                               \
        }                                                                            \
    };                                                                               \
    float sB[4];                                                                     \
    _Pragma("unroll")                                                                \
    for (int n = 0; n < 4; ++n) sB[n] = Sc[n0 + wc * 64 + n * 16 + lr];              \
    f32x4 acc[8][4];                                                                 \
    _Pragma("unroll")                                                                \
    for (int m = 0; m < 8; ++m)                                                      \
        _Pragma("unroll")                                                            \
        for (int n = 0; n < 4; ++n) acc[m][n] = (f32x4){0.f, 0.f, 0.f, 0.f};         \
    STAGE_A(0, 0); STAGE_B(0, 0);                                                    \
    STAGE_A(0, 1); STAGE_B(0, 1);                                                    \
    STAGE_A(1, 0); STAGE_B(1, 0);                                                    \
    asm volatile("s_waitcnt vmcnt(6)" ::: "memory");                                 \
    __builtin_amdgcn_s_barrier();

#define GEMM_KLOOP_BODY                                                              \
    for (int t = 0; t < NT; ++t) {                                                   \
        const int buf = t & 1;                                                       \
        const unsigned short* a0p = As + ((buf << 1) << 13) + aboff + ck;            \
        const unsigned short* a1p = As + (((buf << 1) | 1) << 13) + aboff + ck;      \
        const unsigned char*  bq0 = Bs + ((buf << 1) << 13) + bboff;                 \
        const unsigned char*  bq1 = Bs + (((buf << 1) | 1) << 13) + bboff;           \
        /* Q1: raw b0 + aL0 reads; stage A-k1(t+1) */                                \
        u32x2 b0r[4]; short8 aL0[4], b0[4];                                          \
        _Pragma("unroll")                                                            \
        for (int n = 0; n < 4; ++n) b0r[n] = *(const u32x2*)(bq0 + (n << 9));        \
        _Pragma("unroll")                                                            \
        for (int m = 0; m < 4; ++m) aL0[m] = *(const short8*)(a0p + (m << 9));       \
        STAGE_A(t + 1, 1);                                                           \
        PH_OPEN                                                                      \
        _Pragma("unroll")                                                            \
        for (int n = 0; n < 4; ++n) b0[n] = deq8(b0r[n]);                            \
        _Pragma("unroll")                                                            \
        for (int m = 0; m < 4; ++m)                                                  \
            _Pragma("unroll")                                                        \
            for (int n = 0; n < 4; ++n)                                              \
                acc[m][n] = __builtin_amdgcn_mfma_f32_16x16x32_bf16(aL0[m], b0[n], acc[m][n], 0, 0, 0); \
        PH_CLOSE                                                                     \
        /* Q2: aH0 reads; stage B-k1(t+1) */                                         \
        short8 aH0[4];                                                               \
        _Pragma("unroll")                                                            \
        for (int m = 0; m < 4; ++m) aH0[m] = *(const short8*)(a0p + ((m + 4) << 9)); \
        STAGE_B(t + 1, 1);                                                           \
        PH_OPEN                                                                      \
        _Pragma("unroll")                                                            \
        for (int m = 0; m < 4; ++m)                                                  \
            _Pragma("unroll")                                                        \
            for (int n = 0; n < 4; ++n)                                              \
                acc[m + 4][n] = __builtin_amdgcn_mfma_f32_16x16x32_bf16(aH0[m], b0[n], acc[m + 4][n], 0, 0, 0); \
        if (t < NT - 1) { PH_CLOSE_VM(6) } else { PH_CLOSE_VM(0) }                   \
        /* Q3: raw b1 + aL1 reads; stage A-k0(t+2) */                                \
        u32x2 b1r[4]; short8 aL1[4], b1[4];                                          \
        _Pragma("unroll")                                                            \
        for (int n = 0; n < 4; ++n) b1r[n] = *(const u32x2*)(bq1 + (n << 9));        \
        _Pragma("unroll")                                                            \
        for (int m = 0; m < 4; ++m) aL1[m] = *(const short8*)(a1p + (m << 9));       \
        STAGE_A(t + 2, 0);                                                           \
        PH_OPEN                                                                      \
        _Pragma("unroll")                                                            \
        for (int n = 0; n < 4; ++n) b1[n] = deq8(b1r[n]);                            \
        _Pragma("unroll")                                                            \
        for (int m = 0; m < 4; ++m)                                                  \
            _Pragma("unroll")                                                        \
            for (int n = 0; n < 4; ++n)                                              \
                acc[m][n] = __builtin_amdgcn_mfma_f32_16x16x32_bf16(aL1[m], b1[n], acc[m][n], 0, 0, 0); \
        PH_CLOSE                                                                     \
        /* Q4: aH1 reads; stage B-k0(t+2) */                                         \
        short8 aH1[4];                                                               \
        _Pragma("unroll")                                                            \
        for (int m = 0; m < 4; ++m) aH1[m] = *(const short8*)(a1p + ((m + 4) << 9)); \
        STAGE_B(t + 2, 0);                                                           \
        PH_OPEN                                                                      \
        _Pragma("unroll")                                                            \
        for (int m = 0; m < 4; ++m)                                                  \
            _Pragma("unroll")                                                        \
            for (int n = 0; n < 4; ++n)                                              \
                acc[m + 4][n] = __builtin_amdgcn_mfma_f32_16x16x32_bf16(aH1[m], b1[n], acc[m + 4][n], 0, 0, 0); \
        if (t < NT - 2) { PH_CLOSE_VM(6) } else { PH_CLOSE_VM(3) }                   \
    }

// ---- fused gate+up: H[M][HID] bf16 = silu(X@Wg^T)*(X@Wu^T) ----
__global__ __launch_bounds__(512, 1) void gemm_gateup(
    const unsigned short* __restrict__ X,
    const unsigned char* __restrict__ Wp8,
    const float* __restrict__ sWp,
    unsigned short* __restrict__ H)
{
    __shared__ __attribute__((aligned(16))) unsigned short As[2 * 2 * 8192];
    __shared__ __attribute__((aligned(16))) unsigned char  Bs[2 * 2 * 8192];
    const int NT = DIM / 64;  // 32
    GEMM_PROLOGUE_COMMON(X, Wp8, sWp, PDIM, PDIM)
    GEMM_KLOOP_BODY

    const int lg = lane >> 4;
    #pragma unroll
    for (int m = 0; m < 8; ++m) {
        #pragma unroll
        for (int i = 0; i < 2; ++i) {
            f32x4 g = acc[m][2 * i], u = acc[m][2 * i + 1];
            const int col = (blockIdx.y << 7) + wc * 32 + i * 16 + lr;
            #pragma unroll
            for (int e = 0; e < 4; ++e) {
                const int row = m0 + wr * 128 + m * 16 + lg * 4 + e;
                float gv = g[e] * sB[2 * i];
                float uv = u[e] * sB[2 * i + 1];
                float sg = gv / (1.0f + __expf(-gv));
                H[(size_t)row * HID + col] = f32_to_bf16_rne(sg * uv);
            }
        }
    }
}

// ---- down: Out[M][DIM] f32 = H @ Wd^T ----
__global__ __launch_bounds__(512, 1) void gemm_down(
    const unsigned short* __restrict__ Hb,
    const unsigned char* __restrict__ Wd8,
    const float* __restrict__ sD,
    float* __restrict__ Out)
{
    __shared__ __attribute__((aligned(16))) unsigned short As[2 * 2 * 8192];
    __shared__ __attribute__((aligned(16))) unsigned char  Bs[2 * 2 * 8192];
    const int NT = HID / 64;  // 88
    GEMM_PROLOGUE_COMMON(Hb, Wd8, sD, HID, HID)
    GEMM_KLOOP_BODY

    const int lg = lane >> 4;
    #pragma unroll
    for (int m = 0; m < 8; ++m) {
        #pragma unroll
        for (int n = 0; n < 4; ++n) {
            const int col = n0 + wc * 64 + n * 16 + lr;
            #pragma unroll
            for (int e = 0; e < 4; ++e) {
                const int row = m0 + wr * 128 + m * 16 + lg * 4 + e;
                Out[(size_t)row * DIM + col] = acc[m][n][e] * sB[n];
            }
        }
    }
}

extern "C" void kernel_launch(void* const* d_in, const int* in_sizes, int n_in,
                              void* d_out, int out_size, void* d_ws, size_t ws_size,
                              hipStream_t stream) {
    const float* x      = (const float*)d_in[0];
    const int* wq_gate  = (const int*)d_in[1];
    const float* s_gate = (const float*)d_in[2];
    const int* wq_up    = (const int*)d_in[3];
    const float* s_up   = (const float*)d_in[4];
    const int* wq_down  = (const int*)d_in[5];
    const float* s_down = (const float*)d_in[6];
    float* out = (float*)d_out;

    const int M = in_sizes[0] / DIM;  // 8192

    // ws layout: xb bf16 [M][PDIM] | wgu8 u8 [2*HID][PDIM] (down Wd8 aliases) | sWp f32 [2*HID] | h bf16 [M][HID]
    char* ws = (char*)d_ws;
    unsigned short* xb   = (unsigned short*)ws;
    unsigned char*  wgu8 = (unsigned char*)(ws + (size_t)M * PDIM * 2);
    float*          sWp  = (float*)(ws + (size_t)M * PDIM * 2 + (size_t)2 * HID * PDIM);
    unsigned short* h    = (unsigned short*)(ws + (size_t)M * PDIM * 2 + (size_t)2 * HID * PDIM + (size_t)2 * HID * 4);

    cast_f32_bf16<<<2048, 256, 0, stream>>>(x, xb, (long)M * DIM);
    repack_gateup<<<2048, 256, 0, stream>>>(wq_gate, s_gate, wq_up, s_up, wgu8, sWp);

    gemm_gateup<<<dim3(M / 256, (2 * HID) / 256), 512, 0, stream>>>(xb, wgu8, sWp, h);

    // reuse wgu8 region for down weights (stream-ordered; plain [DIM][HID] u8)
    repack_plain<<<2048, 256, 0, stream>>>(wq_down, wgu8, (long)DIM * HID);

    gemm_down<<<dim3(M / 256, DIM / 256), 512, 0, stream>>>(h, wgu8, s_down, out);
}

// Round 10
// 608.781 us; speedup vs baseline: 1.1553x; 1.1553x over previous
//
#include <hip/hip_runtime.h>
#include <hip/hip_bf16.h>
#include <stdint.h>

#define DIM 2048
#define HID 5632

typedef __attribute__((ext_vector_type(8))) short short8;
typedef __attribute__((ext_vector_type(4))) float f32x4;
typedef __attribute__((ext_vector_type(4))) int int4v;
typedef __attribute__((ext_vector_type(4))) unsigned short ushort4v;

__device__ __forceinline__ unsigned short f32_to_bf16_rne(float f) {
    union { float f; unsigned u; } v; v.f = f;
    unsigned u = v.u;
    return (unsigned short)((u + 0x7FFFu + ((u >> 16) & 1u)) >> 16);
}

__device__ __forceinline__ void gload16(const void* g, void* l) {
    __builtin_amdgcn_global_load_lds(
        (const __attribute__((address_space(1))) void*)g,
        (__attribute__((address_space(3))) void*)l,
        16, 0, 0);
}

// ---- dequant down weights (plain row-major, bf16) ----
__global__ void dequant_plain(const int* __restrict__ wq, const float* __restrict__ scale,
                              unsigned short* __restrict__ out, long total, int cols) {
    long n4 = total >> 2;
    long stride = (long)gridDim.x * blockDim.x;
    for (long i = (long)blockIdx.x * blockDim.x + threadIdx.x; i < n4; i += stride) {
        int4v c = ((const int4v*)wq)[i];
        int row = (int)((i << 2) / cols);
        float s = scale[row];
        ushort4v o;
        o.x = f32_to_bf16_rne(((float)c.x - 128.0f) * s);
        o.y = f32_to_bf16_rne(((float)c.y - 128.0f) * s);
        o.z = f32_to_bf16_rne(((float)c.z - 128.0f) * s);
        o.w = f32_to_bf16_rne(((float)c.w - 128.0f) * s);
        ((ushort4v*)out)[i] = o;
    }
}

// ---- dequant gate+up into 16-row-interleaved W' [2*HID][DIM] bf16 ----
__global__ void dequant_gateup(const int* __restrict__ wg, const float* __restrict__ sg,
                               const int* __restrict__ wu, const float* __restrict__ su,
                               unsigned short* __restrict__ out) {
    const long n4 = (long)HID * DIM / 4;
    long stride = (long)gridDim.x * blockDim.x;
    for (long i = (long)blockIdx.x * blockDim.x + threadIdx.x; i < n4; i += stride) {
        int r  = (int)(i >> 9);
        int c4 = (int)(i & 511);
        int rp = ((r >> 4) << 5) + (r & 15);
        float s1 = sg[r], s2 = su[r];
        int4v g = ((const int4v*)wg)[i];
        int4v u = ((const int4v*)wu)[i];
        ushort4v og, ou;
        og.x = f32_to_bf16_rne(((float)g.x - 128.0f) * s1);
        og.y = f32_to_bf16_rne(((float)g.y - 128.0f) * s1);
        og.z = f32_to_bf16_rne(((float)g.z - 128.0f) * s1);
        og.w = f32_to_bf16_rne(((float)g.w - 128.0f) * s1);
        ou.x = f32_to_bf16_rne(((float)u.x - 128.0f) * s2);
        ou.y = f32_to_bf16_rne(((float)u.y - 128.0f) * s2);
        ou.z = f32_to_bf16_rne(((float)u.z - 128.0f) * s2);
        ou.w = f32_to_bf16_rne(((float)u.w - 128.0f) * s2);
        ((ushort4v*)out)[(long)rp * 512 + c4]        = og;
        ((ushort4v*)out)[(long)(rp + 16) * 512 + c4] = ou;
    }
}

// ---- x: f32 -> bf16 ----
__global__ void cast_f32_bf16(const float* __restrict__ in, unsigned short* __restrict__ out, long n) {
    long n4 = n >> 2;
    long stride = (long)gridDim.x * blockDim.x;
    for (long i = (long)blockIdx.x * blockDim.x + threadIdx.x; i < n4; i += stride) {
        f32x4 v = ((const f32x4*)in)[i];
        ushort4v o;
        o.x = f32_to_bf16_rne(v[0]);
        o.y = f32_to_bf16_rne(v[1]);
        o.z = f32_to_bf16_rne(v[2]);
        o.w = f32_to_bf16_rne(v[3]);
        ((ushort4v*)out)[i] = o;
    }
}

// =====================================================================
// R2 structure (best measured): 256x256 BK=64 double-buffered, XOR-swizzled
// LDS, counted vmcnt(8), setprio MFMA clusters, end-of-tile STAGE(kt+2).
// NEW (T1): 1-D grid + bijective chunked XCD swizzle:
//   wg = (bid%8)*(nwg/8) + bid/8 ; bx = wg%32 (x fastest), by = wg/32.
// Effect: the 32 resident blocks of one XCD share ONE B n-panel at a time
// (L2-resident, fetched once per XCD) instead of 8 thrashing panels.
// 512 threads = 8 waves (2Mx4N), wave tile 128x64.
// =====================================================================

// ---- fused gate+up: H[M][HID] bf16 = silu(X@Wg^T)*(X@Wu^T), W' interleaved ----
__global__ __launch_bounds__(512, 2) void gemm_gateup(
    const unsigned short* __restrict__ X,
    const unsigned short* __restrict__ Wp,
    unsigned short* __restrict__ H)
{
    __shared__ __attribute__((aligned(16))) unsigned short As[2][256 * 64];
    __shared__ __attribute__((aligned(16))) unsigned short Bs[2][256 * 64];

    // T1 chunked XCD swizzle (nwg = 1408, q = 176; 32 x-panels)
    const int q  = (int)(gridDim.x >> 3);
    const int wg = (blockIdx.x & 7) * q + (blockIdx.x >> 3);
    const int bx = wg & 31;
    const int by = wg >> 5;

    const int tid  = threadIdx.x;
    const int lane = tid & 63;
    const int wid  = tid >> 6;
    const int wr   = wid >> 2;
    const int wc   = wid & 3;
    const int m0   = bx << 8;
    const int n0   = by << 8;
    const int lr   = lane & 15;
    const int kg   = lane >> 4;

    int srow[4], skc[4], sdst[4];
    #pragma unroll
    for (int l = 0; l < 4; ++l) {
        int p = l * 512 + tid;
        srow[l] = p >> 3;
        skc[l]  = (((p & 7) ^ ((p >> 3) & 7)) << 3);
        sdst[l] = p << 3;
    }

    auto STAGE = [&](int buf, int kt) {
        const int kk = kt << 6;
        #pragma unroll
        for (int l = 0; l < 4; ++l) {
            gload16(X  + (size_t)(m0 + srow[l]) * DIM + kk + skc[l], &As[buf][sdst[l]]);
            gload16(Wp + (size_t)(n0 + srow[l]) * DIM + kk + skc[l], &Bs[buf][sdst[l]]);
        }
    };

    f32x4 acc[8][4];
    #pragma unroll
    for (int m = 0; m < 8; ++m)
        #pragma unroll
        for (int n = 0; n < 4; ++n) acc[m][n] = (f32x4){0.f, 0.f, 0.f, 0.f};

    const int c0 = ((kg ^ (lr & 7)) << 3);
    const int c1 = (((4 + kg) ^ (lr & 7)) << 3);
    const int abase = (wr * 128 + lr) * 64;
    const int bbase = (wc * 64 + lr) * 64;

    STAGE(0, 0);
    STAGE(1, 1);

    const int NT = DIM / 64;  // 32
    for (int kt = 0; kt < NT; ++kt) {
        const int cur = kt & 1;
        if (kt < NT - 1) asm volatile("s_waitcnt vmcnt(8)" ::: "memory");
        else             asm volatile("s_waitcnt vmcnt(0)" ::: "memory");
        __builtin_amdgcn_s_barrier();
        __builtin_amdgcn_sched_barrier(0);

        const unsigned short* ap0 = &As[cur][abase + c0];
        const unsigned short* ap1 = &As[cur][abase + c1];
        const unsigned short* bp0 = &Bs[cur][bbase + c0];
        const unsigned short* bp1 = &Bs[cur][bbase + c1];

        short8 a0[8], a1[8], b0[4], b1[4];
        #pragma unroll
        for (int n = 0; n < 4; ++n) {
            b0[n] = *(const short8*)(bp0 + (n << 10));
            b1[n] = *(const short8*)(bp1 + (n << 10));
        }
        #pragma unroll
        for (int m = 0; m < 8; ++m) {
            a0[m] = *(const short8*)(ap0 + (m << 10));
            a1[m] = *(const short8*)(ap1 + (m << 10));
        }

        __builtin_amdgcn_s_setprio(1);
        #pragma unroll
        for (int m = 0; m < 8; ++m)
            #pragma unroll
            for (int n = 0; n < 4; ++n)
                acc[m][n] = __builtin_amdgcn_mfma_f32_16x16x32_bf16(a0[m], b0[n], acc[m][n], 0, 0, 0);
        __builtin_amdgcn_s_setprio(0);
        __builtin_amdgcn_s_setprio(1);
        #pragma unroll
        for (int m = 0; m < 8; ++m)
            #pragma unroll
            for (int n = 0; n < 4; ++n)
                acc[m][n] = __builtin_amdgcn_mfma_f32_16x16x32_bf16(a1[m], b1[n], acc[m][n], 0, 0, 0);
        __builtin_amdgcn_s_setprio(0);

        __builtin_amdgcn_sched_barrier(0);
        __builtin_amdgcn_s_barrier();
        __builtin_amdgcn_sched_barrier(0);
        if (kt + 2 < NT) STAGE(cur, kt + 2);
        __builtin_amdgcn_sched_barrier(0);
    }

    // epilogue: n even = gate frag, n odd = up frag (same H columns)
    const int lg = lane >> 4;
    #pragma unroll
    for (int m = 0; m < 8; ++m) {
        #pragma unroll
        for (int i = 0; i < 2; ++i) {
            f32x4 g = acc[m][2 * i], u = acc[m][2 * i + 1];
            const int col = (by << 7) + wc * 32 + i * 16 + lr;
            #pragma unroll
            for (int e = 0; e < 4; ++e) {
                const int row = m0 + wr * 128 + m * 16 + lg * 4 + e;
                float gv = g[e];
                float sg = gv / (1.0f + __expf(-gv));
                H[(size_t)row * HID + col] = f32_to_bf16_rne(sg * u[e]);
            }
        }
    }
}

// ---- down: Out[M][DIM] f32 = H @ Wd^T ----
__global__ __launch_bounds__(512, 2) void gemm_down(
    const unsigned short* __restrict__ Hb,
    const unsigned short* __restrict__ Wd,
    float* __restrict__ Out)
{
    __shared__ __attribute__((aligned(16))) unsigned short As[2][256 * 64];
    __shared__ __attribute__((aligned(16))) unsigned short Bs[2][256 * 64];

    // T1 chunked XCD swizzle (nwg = 256, q = 32; 32 x-panels)
    const int q  = (int)(gridDim.x >> 3);
    const int wg = (blockIdx.x & 7) * q + (blockIdx.x >> 3);
    const int bx = wg & 31;
    const int by = wg >> 5;

    const int tid  = threadIdx.x;
    const int lane = tid & 63;
    const int wid  = tid >> 6;
    const int wr   = wid >> 2;
    const int wc   = wid & 3;
    const int m0   = bx << 8;
    const int n0   = by << 8;
    const int lr   = lane & 15;
    const int kg   = lane >> 4;

    int srow[4], skc[4], sdst[4];
    #pragma unroll
    for (int l = 0; l < 4; ++l) {
        int p = l * 512 + tid;
        srow[l] = p >> 3;
        skc[l]  = (((p & 7) ^ ((p >> 3) & 7)) << 3);
        sdst[l] = p << 3;
    }

    auto STAGE = [&](int buf, int kt) {
        const int kk = kt << 6;
        #pragma unroll
        for (int l = 0; l < 4; ++l) {
            gload16(Hb + (size_t)(m0 + srow[l]) * HID + kk + skc[l], &As[buf][sdst[l]]);
            gload16(Wd + (size_t)(n0 + srow[l]) * HID + kk + skc[l], &Bs[buf][sdst[l]]);
        }
    };

    f32x4 acc[8][4];
    #pragma unroll
    for (int m = 0; m < 8; ++m)
        #pragma unroll
        for (int n = 0; n < 4; ++n) acc[m][n] = (f32x4){0.f, 0.f, 0.f, 0.f};

    const int c0 = ((kg ^ (lr & 7)) << 3);
    const int c1 = (((4 + kg) ^ (lr & 7)) << 3);
    const int abase = (wr * 128 + lr) * 64;
    const int bbase = (wc * 64 + lr) * 64;

    STAGE(0, 0);
    STAGE(1, 1);

    const int NT = HID / 64;  // 88
    for (int kt = 0; kt < NT; ++kt) {
        const int cur = kt & 1;
        if (kt < NT - 1) asm volatile("s_waitcnt vmcnt(8)" ::: "memory");
        else             asm volatile("s_waitcnt vmcnt(0)" ::: "memory");
        __builtin_amdgcn_s_barrier();
        __builtin_amdgcn_sched_barrier(0);

        const unsigned short* ap0 = &As[cur][abase + c0];
        const unsigned short* ap1 = &As[cur][abase + c1];
        const unsigned short* bp0 = &Bs[cur][bbase + c0];
        const unsigned short* bp1 = &Bs[cur][bbase + c1];

        short8 a0[8], a1[8], b0[4], b1[4];
        #pragma unroll
        for (int n = 0; n < 4; ++n) {
            b0[n] = *(const short8*)(bp0 + (n << 10));
            b1[n] = *(const short8*)(bp1 + (n << 10));
        }
        #pragma unroll
        for (int m = 0; m < 8; ++m) {
            a0[m] = *(const short8*)(ap0 + (m << 10));
            a1[m] = *(const short8*)(ap1 + (m << 10));
        }

        __builtin_amdgcn_s_setprio(1);
        #pragma unroll
        for (int m = 0; m < 8; ++m)
            #pragma unroll
            for (int n = 0; n < 4; ++n)
                acc[m][n] = __builtin_amdgcn_mfma_f32_16x16x32_bf16(a0[m], b0[n], acc[m][n], 0, 0, 0);
        __builtin_amdgcn_s_setprio(0);
        __builtin_amdgcn_s_setprio(1);
        #pragma unroll
        for (int m = 0; m < 8; ++m)
            #pragma unroll
            for (int n = 0; n < 4; ++n)
                acc[m][n] = __builtin_amdgcn_mfma_f32_16x16x32_bf16(a1[m], b1[n], acc[m][n], 0, 0, 0);
        __builtin_amdgcn_s_setprio(0);

        __builtin_amdgcn_sched_barrier(0);
        __builtin_amdgcn_s_barrier();
        __builtin_amdgcn_sched_barrier(0);
        if (kt + 2 < NT) STAGE(cur, kt + 2);
        __builtin_amdgcn_sched_barrier(0);
    }

    const int lg = lane >> 4;
    #pragma unroll
    for (int m = 0; m < 8; ++m) {
        #pragma unroll
        for (int n = 0; n < 4; ++n) {
            const int col = n0 + wc * 64 + n * 16 + lr;
            #pragma unroll
            for (int e = 0; e < 4; ++e) {
                const int row = m0 + wr * 128 + m * 16 + lg * 4 + e;
                Out[(size_t)row * DIM + col] = acc[m][n][e];
            }
        }
    }
}

extern "C" void kernel_launch(void* const* d_in, const int* in_sizes, int n_in,
                              void* d_out, int out_size, void* d_ws, size_t ws_size,
                              hipStream_t stream) {
    const float* x      = (const float*)d_in[0];
    const int* wq_gate  = (const int*)d_in[1];
    const float* s_gate = (const float*)d_in[2];
    const int* wq_up    = (const int*)d_in[3];
    const float* s_up   = (const float*)d_in[4];
    const int* wq_down  = (const int*)d_in[5];
    const float* s_down = (const float*)d_in[6];
    float* out = (float*)d_out;

    const int M = in_sizes[0] / DIM;  // 8192

    // ws layout (elems, bf16): xb [M*DIM] | wgu [2*HID*DIM] (down weights alias) | h [M*HID]
    unsigned short* xb  = (unsigned short*)d_ws;
    unsigned short* wgu = xb + (size_t)M * DIM;
    unsigned short* h   = wgu + (size_t)2 * HID * DIM;

    cast_f32_bf16<<<2048, 256, 0, stream>>>(x, xb, (long)M * DIM);
    dequant_gateup<<<2048, 256, 0, stream>>>(wq_gate, s_gate, wq_up, s_up, wgu);

    // 1-D grids (x fastest in wg decode): nwg % 8 == 0 for both
    gemm_gateup<<<(M / 256) * ((2 * HID) / 256), 512, 0, stream>>>(xb, wgu, h);

    dequant_plain<<<2048, 256, 0, stream>>>(wq_down, s_down, wgu, (long)DIM * HID, HID);

    gemm_down<<<(M / 256) * (DIM / 256), 512, 0, stream>>>(h, wgu, out);
}